// Round 2
// baseline (28675.598 us; speedup 1.0000x reference)
//
#include <hip/hip_runtime.h>
#include <math.h>

#define BB 64
#define SS 512
#define EE 256
#define HH 512

#define NBLK 128   // 8 row-slices x 16 batch-chunks
#define NSH  8     // barrier counter shards (64B apart)

// ---------------------------------------------------------------------------
// Projection GEMM: out[m][n] = sum_k A[m][k] * Wih[n][k] + b1[n] + b2[n]
// A row m = (src ? emb[src[m]] : Ain + m*K).  M = BB*SS, N = HH.
// ---------------------------------------------------------------------------
template <int K>
__global__ __launch_bounds__(256) void k_proj(const float* __restrict__ Ain,
                                              const int* __restrict__ src,
                                              const float* __restrict__ emb,
                                              const float* __restrict__ Wih,
                                              const float* __restrict__ b1,
                                              const float* __restrict__ b2,
                                              float* __restrict__ out) {
    __shared__ __align__(16) float As[16][68];
    __shared__ __align__(16) float Bs[16][68];
    int tid = threadIdx.x;
    int m0 = blockIdx.x * 64;
    int n0 = blockIdx.y * 64;
    int tx = tid & 15, ty = tid >> 4;
    int lr = tid >> 2;
    int lc = (tid & 3) * 4;

    const float* arow;
    if (src) arow = emb + (size_t)src[m0 + lr] * EE;
    else     arow = Ain + (size_t)(m0 + lr) * K;
    const float* brow = Wih + (size_t)(n0 + lr) * K;

    float acc[4][4] = {};

    for (int k0 = 0; k0 < K; k0 += 16) {
        float4 av = *(const float4*)(arow + k0 + lc);
        float4 bv = *(const float4*)(brow + k0 + lc);
        __syncthreads();
        As[lc + 0][lr] = av.x; As[lc + 1][lr] = av.y;
        As[lc + 2][lr] = av.z; As[lc + 3][lr] = av.w;
        Bs[lc + 0][lr] = bv.x; Bs[lc + 1][lr] = bv.y;
        Bs[lc + 2][lr] = bv.z; Bs[lc + 3][lr] = bv.w;
        __syncthreads();
#pragma unroll
        for (int k = 0; k < 16; ++k) {
            float4 a = *(const float4*)&As[k][ty * 4];
            float4 b = *(const float4*)&Bs[k][tx * 4];
            acc[0][0] += a.x * b.x; acc[0][1] += a.x * b.y;
            acc[0][2] += a.x * b.z; acc[0][3] += a.x * b.w;
            acc[1][0] += a.y * b.x; acc[1][1] += a.y * b.y;
            acc[1][2] += a.y * b.z; acc[1][3] += a.y * b.w;
            acc[2][0] += a.z * b.x; acc[2][1] += a.z * b.y;
            acc[2][2] += a.z * b.z; acc[2][3] += a.z * b.w;
            acc[3][0] += a.w * b.x; acc[3][1] += a.w * b.y;
            acc[3][2] += a.w * b.z; acc[3][3] += a.w * b.w;
        }
    }

    int n = n0 + tx * 4;
    float bx_ = b1[n + 0] + b2[n + 0];
    float by_ = b1[n + 1] + b2[n + 1];
    float bz_ = b1[n + 2] + b2[n + 2];
    float bw_ = b1[n + 3] + b2[n + 3];
#pragma unroll
    for (int i = 0; i < 4; ++i) {
        int m = m0 + ty * 4 + i;
        float4 o;
        o.x = acc[i][0] + bx_; o.y = acc[i][1] + by_;
        o.z = acc[i][2] + bz_; o.w = acc[i][3] + bw_;
        *(float4*)(out + (size_t)m * HH + n) = o;
    }
}

// ---------------------------------------------------------------------------
// Sharded monotone grid barrier. ctr: NSH counters, 64B apart.
// After barrier #k completes, sum == NBLK*(k+1).
// ---------------------------------------------------------------------------
__device__ __forceinline__ void gbar(unsigned* ctr, int shard, unsigned target, int tid) {
    __threadfence();
    __syncthreads();
    if (tid == 0) {
        __hip_atomic_fetch_add(&ctr[shard], 1u, __ATOMIC_RELEASE, __HIP_MEMORY_SCOPE_AGENT);
        for (;;) {
            unsigned s = 0;
#pragma unroll
            for (int i = 0; i < NSH; ++i)
                s += __hip_atomic_load(&ctr[i * 16], __ATOMIC_RELAXED, __HIP_MEMORY_SCOPE_AGENT);
            if (s >= target) break;
            __builtin_amdgcn_s_sleep(1);
        }
    }
    __syncthreads();
    __threadfence();
}

// ---------------------------------------------------------------------------
// Persistent recurrence. Grid = 128 blocks (8 row-slices x 16 batch-chunks),
// 256 threads = 64 lanes (row r) x 4 waves (k-range w*128).
// W slice lives in 128 VGPRs per thread for the whole kernel.
// h exchanged via global hbuf[2][BB][HH] with agent-scope atomics + barrier.
// ---------------------------------------------------------------------------
__global__ __launch_bounds__(256, 1) void k_rec_p(const float* __restrict__ pre,
                                                  const float* __restrict__ W,
                                                  float* __restrict__ y,
                                                  float* __restrict__ hlast,
                                                  float* __restrict__ hbuf,
                                                  unsigned* __restrict__ ctr) {
    __shared__ __align__(16) float h_lds[4 * HH];      // 4 batches x 512
    __shared__ __align__(16) float red[4][4][64];      // [wave][batch][row]
    const int tid = threadIdx.x;
    const int r = tid & 63;
    const int w = tid >> 6;
    const int bid = blockIdx.x;
    const int g = bid >> 4;          // row slice 0..7
    const int c = bid & 15;          // batch chunk 0..15
    const int grow = g * 64 + r;     // global output row
    const int b = c * 4 + w;         // batch this thread finalizes
    const int shard = (bid & (NSH - 1)) * 16;

    // W slice -> registers (one-time, ~1MB x 16 copies from HBM/L2 total)
    float4 w4[32];
    const float* wrow = W + (size_t)grow * HH + w * 128;
#pragma unroll
    for (int i = 0; i < 32; ++i) w4[i] = *(const float4*)(wrow + i * 4);

    // ---- t = 0: h = tanh(pre), h_prev = 0 (no exchange needed) ----
    float hval;
    {
        float pv = pre[(size_t)b * SS * HH + grow];
        hval = tanhf(pv);
        y[(size_t)b * SS * HH + grow] = hval;
        __hip_atomic_store(&hbuf[(size_t)1 * BB * HH + (size_t)b * HH + grow], hval,
                           __ATOMIC_RELEASE, __HIP_MEMORY_SCOPE_AGENT);
    }
    unsigned target = NBLK;
    gbar(ctr, shard, target, tid);

    for (int t = 1; t < SS; ++t) {
        // stage h_{t} for our 4 batches: 2048 floats, agent-scope loads
        const float* hc = hbuf + (size_t)(t & 1) * BB * HH + (size_t)(c * 4) * HH;
        {
            int i0 = tid * 8;
#pragma unroll
            for (int i = 0; i < 8; ++i)
                h_lds[i0 + i] = __hip_atomic_load(hc + i0 + i, __ATOMIC_RELAXED,
                                                  __HIP_MEMORY_SCOPE_AGENT);
        }
        __syncthreads();

        float pv = pre[((size_t)b * SS + t) * HH + grow];  // prefetch, used post-FMA

        float acc0 = 0.f, acc1 = 0.f, acc2 = 0.f, acc3 = 0.f;
        const float4* h4p = (const float4*)h_lds + w * 32;
#pragma unroll
        for (int i = 0; i < 32; ++i) {
            const float4 a = w4[i];
            const float4 h0 = h4p[i];
            const float4 h1 = h4p[i + 128];
            const float4 h2 = h4p[i + 256];
            const float4 h3 = h4p[i + 384];
            acc0 += a.x * h0.x; acc0 += a.y * h0.y; acc0 += a.z * h0.z; acc0 += a.w * h0.w;
            acc1 += a.x * h1.x; acc1 += a.y * h1.y; acc1 += a.z * h1.z; acc1 += a.w * h1.w;
            acc2 += a.x * h2.x; acc2 += a.y * h2.y; acc2 += a.z * h2.z; acc2 += a.w * h2.w;
            acc3 += a.x * h3.x; acc3 += a.y * h3.y; acc3 += a.z * h3.z; acc3 += a.w * h3.w;
        }
        red[w][0][r] = acc0; red[w][1][r] = acc1;
        red[w][2][r] = acc2; red[w][3][r] = acc3;
        __syncthreads();

        float s = red[0][w][r] + red[1][w][r] + red[2][w][r] + red[3][w][r];
        hval = tanhf(pv + s);
        y[((size_t)b * SS + t) * HH + grow] = hval;
        if (t < SS - 1) {
            __hip_atomic_store(&hbuf[(size_t)((t + 1) & 1) * BB * HH + (size_t)b * HH + grow],
                               hval, __ATOMIC_RELEASE, __HIP_MEMORY_SCOPE_AGENT);
            target += NBLK;
            gbar(ctr, shard, target, tid);
        }
    }
    hlast[(size_t)b * HH + grow] = hval;
}

// ---------------------------------------------------------------------------
extern "C" void kernel_launch(void* const* d_in, const int* in_sizes, int n_in,
                              void* d_out, int out_size, void* d_ws, size_t ws_size,
                              hipStream_t stream) {
    const int*   src   = (const int*)d_in[0];
    const float* emb   = (const float*)d_in[1];
    const float* W_ih0 = (const float*)d_in[2];
    const float* W_hh0 = (const float*)d_in[3];
    const float* b_ih0 = (const float*)d_in[4];
    const float* b_hh0 = (const float*)d_in[5];
    const float* W_ih1 = (const float*)d_in[6];
    const float* W_hh1 = (const float*)d_in[7];
    const float* b_ih1 = (const float*)d_in[8];
    const float* b_hh1 = (const float*)d_in[9];

    float* out   = (float*)d_out;
    float* y_out = out;                               // [B][S][H]
    float* hlast = out + (size_t)BB * SS * HH;        // [2][B][H]

    float*    ws   = (float*)d_ws;
    float*    pre  = ws;                              // [B][S][H]
    float*    hbuf = ws + (size_t)BB * SS * HH;       // [2][B][H]
    unsigned* ctr  = (unsigned*)(hbuf + (size_t)2 * BB * HH);  // 2 layers x 8 shards x 16

    hipMemsetAsync(ctr, 0, 2 * NSH * 16 * sizeof(unsigned), stream);

    // Layer 0
    k_proj<EE><<<dim3(512, 8), 256, 0, stream>>>(nullptr, src, emb, W_ih0,
                                                 b_ih0, b_hh0, pre);
    k_rec_p<<<NBLK, 256, 0, stream>>>(pre, W_hh0, y_out, hlast, hbuf, ctr);

    // Layer 1
    k_proj<HH><<<dim3(512, 8), 256, 0, stream>>>(y_out, nullptr, nullptr, W_ih1,
                                                 b_ih1, b_hh1, pre);
    k_rec_p<<<NBLK, 256, 0, stream>>>(pre, W_hh1, y_out, hlast + (size_t)BB * HH,
                                      hbuf, ctr + NSH * 16);
}

// Round 3
// 6459.597 us; speedup vs baseline: 4.4392x; 4.4392x over previous
//
#include <hip/hip_runtime.h>
#include <math.h>

#define BB 64
#define SS 512
#define EE 256
#define HH 512

#define NBLK 128   // 8 row-slices x 16 batch-chunks
#define NSH  8     // barrier counter shards (64B apart)

// ---------------------------------------------------------------------------
// Projection GEMM: out[m][n] = sum_k A[m][k] * Wih[n][k] + b1[n] + b2[n]
// A row m = (src ? emb[src[m]] : Ain + m*K).  M = BB*SS, N = HH.
// ---------------------------------------------------------------------------
template <int K>
__global__ __launch_bounds__(256) void k_proj(const float* __restrict__ Ain,
                                              const int* __restrict__ src,
                                              const float* __restrict__ emb,
                                              const float* __restrict__ Wih,
                                              const float* __restrict__ b1,
                                              const float* __restrict__ b2,
                                              float* __restrict__ out) {
    __shared__ __align__(16) float As[16][68];
    __shared__ __align__(16) float Bs[16][68];
    int tid = threadIdx.x;
    int m0 = blockIdx.x * 64;
    int n0 = blockIdx.y * 64;
    int tx = tid & 15, ty = tid >> 4;
    int lr = tid >> 2;
    int lc = (tid & 3) * 4;

    const float* arow;
    if (src) arow = emb + (size_t)src[m0 + lr] * EE;
    else     arow = Ain + (size_t)(m0 + lr) * K;
    const float* brow = Wih + (size_t)(n0 + lr) * K;

    float acc[4][4] = {};

    for (int k0 = 0; k0 < K; k0 += 16) {
        float4 av = *(const float4*)(arow + k0 + lc);
        float4 bv = *(const float4*)(brow + k0 + lc);
        __syncthreads();
        As[lc + 0][lr] = av.x; As[lc + 1][lr] = av.y;
        As[lc + 2][lr] = av.z; As[lc + 3][lr] = av.w;
        Bs[lc + 0][lr] = bv.x; Bs[lc + 1][lr] = bv.y;
        Bs[lc + 2][lr] = bv.z; Bs[lc + 3][lr] = bv.w;
        __syncthreads();
#pragma unroll
        for (int k = 0; k < 16; ++k) {
            float4 a = *(const float4*)&As[k][ty * 4];
            float4 b = *(const float4*)&Bs[k][tx * 4];
            acc[0][0] += a.x * b.x; acc[0][1] += a.x * b.y;
            acc[0][2] += a.x * b.z; acc[0][3] += a.x * b.w;
            acc[1][0] += a.y * b.x; acc[1][1] += a.y * b.y;
            acc[1][2] += a.y * b.z; acc[1][3] += a.y * b.w;
            acc[2][0] += a.z * b.x; acc[2][1] += a.z * b.y;
            acc[2][2] += a.z * b.z; acc[2][3] += a.z * b.w;
            acc[3][0] += a.w * b.x; acc[3][1] += a.w * b.y;
            acc[3][2] += a.w * b.z; acc[3][3] += a.w * b.w;
        }
    }

    int n = n0 + tx * 4;
    float bx_ = b1[n + 0] + b2[n + 0];
    float by_ = b1[n + 1] + b2[n + 1];
    float bz_ = b1[n + 2] + b2[n + 2];
    float bw_ = b1[n + 3] + b2[n + 3];
#pragma unroll
    for (int i = 0; i < 4; ++i) {
        int m = m0 + ty * 4 + i;
        float4 o;
        o.x = acc[i][0] + bx_; o.y = acc[i][1] + by_;
        o.z = acc[i][2] + bz_; o.w = acc[i][3] + bw_;
        *(float4*)(out + (size_t)m * HH + n) = o;
    }
}

// ---------------------------------------------------------------------------
// Sharded monotone grid barrier — ALL RELAXED agent atomics (no wbl2/inv).
// Caller guarantees its prior IC-bound stores are drained (s_waitcnt vmcnt(0)).
// After barrier #k completes, sum == NBLK*(k+1).
// ---------------------------------------------------------------------------
__device__ __forceinline__ void gbar(unsigned* ctr, int shard, unsigned target, int tid) {
    asm volatile("s_waitcnt vmcnt(0)" ::: "memory");  // per-wave: drain own h stores
    __syncthreads();                                  // all waves drained
    if (tid == 0) {
        __hip_atomic_fetch_add(&ctr[shard], 1u, __ATOMIC_RELAXED, __HIP_MEMORY_SCOPE_AGENT);
        for (;;) {
            unsigned s = 0;
#pragma unroll
            for (int i = 0; i < NSH; ++i)
                s += __hip_atomic_load(&ctr[i * 16], __ATOMIC_RELAXED, __HIP_MEMORY_SCOPE_AGENT);
            if (s >= target) break;
            __builtin_amdgcn_s_sleep(1);
        }
    }
    __syncthreads();
}

// ---------------------------------------------------------------------------
// Persistent recurrence. Grid = 128 blocks (8 row-slices x 16 batch-chunks),
// 256 threads = 64 lanes (row r) x 4 waves (k-range w*128).
// W slice lives in registers for the whole kernel.
// h exchanged via hbuf with RELAXED agent atomics (IC write-through/bypass).
// ---------------------------------------------------------------------------
__global__ __launch_bounds__(256, 1) void k_rec_p(const float* __restrict__ pre,
                                                  const float* __restrict__ W,
                                                  float* __restrict__ y,
                                                  float* __restrict__ hlast,
                                                  float* __restrict__ hbuf,
                                                  unsigned* __restrict__ ctr) {
    __shared__ __align__(16) float h_lds[4 * HH];      // 4 batches x 512
    __shared__ __align__(16) float red[4][4][64];      // [wave][batch][row]
    const int tid = threadIdx.x;
    const int r = tid & 63;
    const int w = tid >> 6;
    const int bid = blockIdx.x;
    const int g = bid >> 4;          // row slice 0..7
    const int c = bid & 15;          // batch chunk 0..15
    const int grow = g * 64 + r;     // global output row
    const int b = c * 4 + w;         // batch this thread finalizes
    const int shard = (bid & (NSH - 1)) * 16;

    // W slice -> registers (one-time)
    float4 w4[32];
    const float* wrow = W + (size_t)grow * HH + w * 128;
#pragma unroll
    for (int i = 0; i < 32; ++i) w4[i] = *(const float4*)(wrow + i * 4);

    // ---- t = 0: h = tanh(pre), h_prev = 0 (no exchange needed) ----
    float hval;
    {
        float pv = pre[(size_t)b * SS * HH + grow];
        hval = tanhf(pv);
        y[(size_t)b * SS * HH + grow] = hval;
        __hip_atomic_store(&hbuf[(size_t)1 * BB * HH + (size_t)b * HH + grow], hval,
                           __ATOMIC_RELAXED, __HIP_MEMORY_SCOPE_AGENT);
    }
    unsigned target = NBLK;
    gbar(ctr, shard, target, tid);

    for (int t = 1; t < SS; ++t) {
        // stage h_t for our 4 batches: 2048 floats, coalesced + stride-1 LDS
        const float* hc = hbuf + (size_t)(t & 1) * BB * HH + (size_t)(c * 4) * HH;
#pragma unroll
        for (int i = 0; i < 8; ++i)
            h_lds[tid + 256 * i] = __hip_atomic_load(hc + tid + 256 * i, __ATOMIC_RELAXED,
                                                     __HIP_MEMORY_SCOPE_AGENT);
        __syncthreads();

        float pv = pre[((size_t)b * SS + t) * HH + grow];  // prefetch, used post-FMA

        float acc0 = 0.f, acc1 = 0.f, acc2 = 0.f, acc3 = 0.f;
        const float4* h4p = (const float4*)h_lds + w * 32;
#pragma unroll
        for (int i = 0; i < 32; ++i) {
            const float4 a = w4[i];
            const float4 h0 = h4p[i];
            const float4 h1 = h4p[i + 128];
            const float4 h2 = h4p[i + 256];
            const float4 h3 = h4p[i + 384];
            acc0 += a.x * h0.x; acc0 += a.y * h0.y; acc0 += a.z * h0.z; acc0 += a.w * h0.w;
            acc1 += a.x * h1.x; acc1 += a.y * h1.y; acc1 += a.z * h1.z; acc1 += a.w * h1.w;
            acc2 += a.x * h2.x; acc2 += a.y * h2.y; acc2 += a.z * h2.z; acc2 += a.w * h2.w;
            acc3 += a.x * h3.x; acc3 += a.y * h3.y; acc3 += a.z * h3.z; acc3 += a.w * h3.w;
        }
        red[w][0][r] = acc0; red[w][1][r] = acc1;
        red[w][2][r] = acc2; red[w][3][r] = acc3;
        __syncthreads();

        float s = red[0][w][r] + red[1][w][r] + red[2][w][r] + red[3][w][r];
        hval = tanhf(pv + s);
        y[((size_t)b * SS + t) * HH + grow] = hval;
        if (t < SS - 1) {
            __hip_atomic_store(&hbuf[(size_t)((t + 1) & 1) * BB * HH + (size_t)b * HH + grow],
                               hval, __ATOMIC_RELAXED, __HIP_MEMORY_SCOPE_AGENT);
            target += NBLK;
            gbar(ctr, shard, target, tid);
        }
    }
    hlast[(size_t)b * HH + grow] = hval;
}

// ---------------------------------------------------------------------------
extern "C" void kernel_launch(void* const* d_in, const int* in_sizes, int n_in,
                              void* d_out, int out_size, void* d_ws, size_t ws_size,
                              hipStream_t stream) {
    const int*   src   = (const int*)d_in[0];
    const float* emb   = (const float*)d_in[1];
    const float* W_ih0 = (const float*)d_in[2];
    const float* W_hh0 = (const float*)d_in[3];
    const float* b_ih0 = (const float*)d_in[4];
    const float* b_hh0 = (const float*)d_in[5];
    const float* W_ih1 = (const float*)d_in[6];
    const float* W_hh1 = (const float*)d_in[7];
    const float* b_ih1 = (const float*)d_in[8];
    const float* b_hh1 = (const float*)d_in[9];

    float* out   = (float*)d_out;
    float* y_out = out;                               // [B][S][H]
    float* hlast = out + (size_t)BB * SS * HH;        // [2][B][H]

    float*    ws   = (float*)d_ws;
    float*    pre  = ws;                              // [B][S][H]
    float*    hbuf = ws + (size_t)BB * SS * HH;       // [2][B][H]
    unsigned* ctr  = (unsigned*)(hbuf + (size_t)2 * BB * HH);  // 2 layers x 8 shards x 16

    hipMemsetAsync(ctr, 0, 2 * NSH * 16 * sizeof(unsigned), stream);

    // Layer 0
    k_proj<EE><<<dim3(512, 8), 256, 0, stream>>>(nullptr, src, emb, W_ih0,
                                                 b_ih0, b_hh0, pre);
    k_rec_p<<<NBLK, 256, 0, stream>>>(pre, W_hh0, y_out, hlast, hbuf, ctr);

    // Layer 1
    k_proj<HH><<<dim3(512, 8), 256, 0, stream>>>(y_out, nullptr, nullptr, W_ih1,
                                                 b_ih1, b_hh1, pre);
    k_rec_p<<<NBLK, 256, 0, stream>>>(pre, W_hh1, y_out, hlast + (size_t)BB * HH,
                                      hbuf, ctr + NSH * 16);
}

// Round 4
// 6111.608 us; speedup vs baseline: 4.6920x; 1.0569x over previous
//
#include <hip/hip_runtime.h>
#include <math.h>

#define BB 64
#define SS 512
#define EE 256
#define HH 512

#define NGRP 16    // independent batch-chunk groups (4 batches each)
#define GSZ  8     // row-slice blocks per group
#define NBLK (NGRP * GSZ)

// ---------------------------------------------------------------------------
// Projection GEMM: out[m][n] = sum_k A[m][k] * Wih[n][k] + b1[n] + b2[n]
// A row m = (src ? emb[src[m]] : Ain + m*K).  M = BB*SS, N = HH.
// ---------------------------------------------------------------------------
template <int K>
__global__ __launch_bounds__(256) void k_proj(const float* __restrict__ Ain,
                                              const int* __restrict__ src,
                                              const float* __restrict__ emb,
                                              const float* __restrict__ Wih,
                                              const float* __restrict__ b1,
                                              const float* __restrict__ b2,
                                              float* __restrict__ out) {
    __shared__ __align__(16) float As[16][68];
    __shared__ __align__(16) float Bs[16][68];
    int tid = threadIdx.x;
    int m0 = blockIdx.x * 64;
    int n0 = blockIdx.y * 64;
    int tx = tid & 15, ty = tid >> 4;
    int lr = tid >> 2;
    int lc = (tid & 3) * 4;

    const float* arow;
    if (src) arow = emb + (size_t)src[m0 + lr] * EE;
    else     arow = Ain + (size_t)(m0 + lr) * K;
    const float* brow = Wih + (size_t)(n0 + lr) * K;

    float acc[4][4] = {};

    for (int k0 = 0; k0 < K; k0 += 16) {
        float4 av = *(const float4*)(arow + k0 + lc);
        float4 bv = *(const float4*)(brow + k0 + lc);
        __syncthreads();
        As[lc + 0][lr] = av.x; As[lc + 1][lr] = av.y;
        As[lc + 2][lr] = av.z; As[lc + 3][lr] = av.w;
        Bs[lc + 0][lr] = bv.x; Bs[lc + 1][lr] = bv.y;
        Bs[lc + 2][lr] = bv.z; Bs[lc + 3][lr] = bv.w;
        __syncthreads();
#pragma unroll
        for (int k = 0; k < 16; ++k) {
            float4 a = *(const float4*)&As[k][ty * 4];
            float4 b = *(const float4*)&Bs[k][tx * 4];
            acc[0][0] += a.x * b.x; acc[0][1] += a.x * b.y;
            acc[0][2] += a.x * b.z; acc[0][3] += a.x * b.w;
            acc[1][0] += a.y * b.x; acc[1][1] += a.y * b.y;
            acc[1][2] += a.y * b.z; acc[1][3] += a.y * b.w;
            acc[2][0] += a.z * b.x; acc[2][1] += a.z * b.y;
            acc[2][2] += a.z * b.z; acc[2][3] += a.z * b.w;
            acc[3][0] += a.w * b.x; acc[3][1] += a.w * b.y;
            acc[3][2] += a.w * b.z; acc[3][3] += a.w * b.w;
        }
    }

    int n = n0 + tx * 4;
    float bx_ = b1[n + 0] + b2[n + 0];
    float by_ = b1[n + 1] + b2[n + 1];
    float bz_ = b1[n + 2] + b2[n + 2];
    float bw_ = b1[n + 3] + b2[n + 3];
#pragma unroll
    for (int i = 0; i < 4; ++i) {
        int m = m0 + ty * 4 + i;
        float4 o;
        o.x = acc[i][0] + bx_; o.y = acc[i][1] + by_;
        o.z = acc[i][2] + bz_; o.w = acc[i][3] + bw_;
        *(float4*)(out + (size_t)m * HH + n) = o;
    }
}

// ---------------------------------------------------------------------------
// Persistent recurrence with GROUP-LOCAL sync.
// Grid = 128 blocks = 16 groups (batch chunks of 4) x 8 row-slice blocks.
// 256 threads = 64 lanes (row r) x 4 waves (k-quarter for compute; batch for
// finalize). W slice (64 rows x 512) lives in 128 VGPRs/thread.
// Exchange: h slices via IC-bypass (relaxed agent) stores/loads; readiness via
// per-(group,slice) epoch flags: flag[c][g] = #published steps.
// 2-slot hbuf is safe: publishing h_t implies h_{t-1} was consumed, and a slot
// is only overwritten two steps later, gated by all 8 flags.
// ---------------------------------------------------------------------------
__global__ __launch_bounds__(256, 1) void k_rec_p(const float* __restrict__ pre,
                                                  const float* __restrict__ W,
                                                  float* __restrict__ y,
                                                  float* __restrict__ hlast,
                                                  float* __restrict__ hbuf,
                                                  unsigned* __restrict__ flags) {
    __shared__ __align__(16) float h_lds[4 * HH];      // 4 batches x 512
    __shared__ __align__(16) float red[4][4][64];      // [kq][batch][row]
    const int tid = threadIdx.x;
    const int r = tid & 63;
    const int w = tid >> 6;
    const int bid = blockIdx.x;
    const int g = bid >> 4;          // row slice 0..7
    const int c = bid & 15;          // batch chunk 0..15
    const int grow = g * 64 + r;     // global output row
    const int b = c * 4 + w;         // batch this thread finalizes
    unsigned* gflags = flags + c * 32;   // 128B-separated per group

    // W slice -> registers (one-time)
    float4 w4[32];
    const float* wrow = W + (size_t)grow * HH + w * 128;
#pragma unroll
    for (int i = 0; i < 32; ++i) w4[i] = *(const float4*)(wrow + i * 4);

    // ---- t = 0: h = tanh(pre), h_prev = 0 (no exchange needed) ----
    float hval;
    {
        float pv = pre[(size_t)b * SS * HH + grow];
        hval = tanhf(pv);
        y[(size_t)b * SS * HH + grow] = hval;
        __hip_atomic_store(&hbuf[(size_t)1 * BB * HH + (size_t)b * HH + grow], hval,
                           __ATOMIC_RELAXED, __HIP_MEMORY_SCOPE_AGENT);
    }
    asm volatile("s_waitcnt vmcnt(0)" ::: "memory");   // h store reached IC
    __syncthreads();
    if (tid == 0)
        __hip_atomic_store(&gflags[g], 1u, __ATOMIC_RELAXED, __HIP_MEMORY_SCOPE_AGENT);

    for (int t = 1; t < SS; ++t) {
        // prefetch pre[b][t][grow] — latency hides under the flag wait
        float pv = pre[((size_t)b * SS + t) * HH + grow];

        // wait for all 8 slices of our group's h_{t-1} (one cacheline of flags)
        if (tid < GSZ) {
            while (__hip_atomic_load(&gflags[tid], __ATOMIC_RELAXED,
                                     __HIP_MEMORY_SCOPE_AGENT) < (unsigned)t)
                __builtin_amdgcn_s_sleep(1);
        }
        __syncthreads();

        // stage h_{t-1} for our 4 batches: 2048 floats, coalesced, stride-1 LDS
        const float* hc = hbuf + (size_t)(t & 1) * BB * HH + (size_t)(c * 4) * HH;
#pragma unroll
        for (int i = 0; i < 8; ++i)
            h_lds[tid + 256 * i] = __hip_atomic_load(hc + tid + 256 * i, __ATOMIC_RELAXED,
                                                     __HIP_MEMORY_SCOPE_AGENT);
        __syncthreads();

        float acc0 = 0.f, acc1 = 0.f, acc2 = 0.f, acc3 = 0.f;
        const float4* h4p = (const float4*)h_lds + w * 32;
#pragma unroll
        for (int i = 0; i < 32; ++i) {
            const float4 a = w4[i];
            const float4 h0 = h4p[i];
            const float4 h1 = h4p[i + 128];
            const float4 h2 = h4p[i + 256];
            const float4 h3 = h4p[i + 384];
            acc0 += a.x * h0.x; acc0 += a.y * h0.y; acc0 += a.z * h0.z; acc0 += a.w * h0.w;
            acc1 += a.x * h1.x; acc1 += a.y * h1.y; acc1 += a.z * h1.z; acc1 += a.w * h1.w;
            acc2 += a.x * h2.x; acc2 += a.y * h2.y; acc2 += a.z * h2.z; acc2 += a.w * h2.w;
            acc3 += a.x * h3.x; acc3 += a.y * h3.y; acc3 += a.z * h3.z; acc3 += a.w * h3.w;
        }
        red[w][0][r] = acc0; red[w][1][r] = acc1;
        red[w][2][r] = acc2; red[w][3][r] = acc3;
        __syncthreads();

        float s = red[0][w][r] + red[1][w][r] + red[2][w][r] + red[3][w][r];
        hval = tanhf(pv + s);
        y[((size_t)b * SS + t) * HH + grow] = hval;
        if (t < SS - 1) {
            __hip_atomic_store(&hbuf[(size_t)((t + 1) & 1) * BB * HH + (size_t)b * HH + grow],
                               hval, __ATOMIC_RELAXED, __HIP_MEMORY_SCOPE_AGENT);
            asm volatile("s_waitcnt vmcnt(0)" ::: "memory");   // h (and y) drained to IC
            __syncthreads();
            if (tid == 0)
                __hip_atomic_store(&gflags[g], (unsigned)(t + 1),
                                   __ATOMIC_RELAXED, __HIP_MEMORY_SCOPE_AGENT);
        }
    }
    hlast[(size_t)b * HH + grow] = hval;
}

// ---------------------------------------------------------------------------
extern "C" void kernel_launch(void* const* d_in, const int* in_sizes, int n_in,
                              void* d_out, int out_size, void* d_ws, size_t ws_size,
                              hipStream_t stream) {
    const int*   src   = (const int*)d_in[0];
    const float* emb   = (const float*)d_in[1];
    const float* W_ih0 = (const float*)d_in[2];
    const float* W_hh0 = (const float*)d_in[3];
    const float* b_ih0 = (const float*)d_in[4];
    const float* b_hh0 = (const float*)d_in[5];
    const float* W_ih1 = (const float*)d_in[6];
    const float* W_hh1 = (const float*)d_in[7];
    const float* b_ih1 = (const float*)d_in[8];
    const float* b_hh1 = (const float*)d_in[9];

    float* out   = (float*)d_out;
    float* y_out = out;                               // [B][S][H]
    float* hlast = out + (size_t)BB * SS * HH;        // [2][B][H]

    float*    ws    = (float*)d_ws;
    float*    pre   = ws;                             // [B][S][H]
    float*    hbuf  = ws + (size_t)BB * SS * HH;      // [2][B][H]
    unsigned* flags = (unsigned*)(hbuf + (size_t)2 * BB * HH);  // 2 layers x 16 grp x 32

    hipMemsetAsync(flags, 0, 2 * NGRP * 32 * sizeof(unsigned), stream);

    // Layer 0
    k_proj<EE><<<dim3(512, 8), 256, 0, stream>>>(nullptr, src, emb, W_ih0,
                                                 b_ih0, b_hh0, pre);
    k_rec_p<<<NBLK, 256, 0, stream>>>(pre, W_hh0, y_out, hlast, hbuf, flags);

    // Layer 1
    k_proj<HH><<<dim3(512, 8), 256, 0, stream>>>(y_out, nullptr, nullptr, W_ih1,
                                                 b_ih1, b_hh1, pre);
    k_rec_p<<<NBLK, 256, 0, stream>>>(pre, W_hh1, y_out, hlast + (size_t)BB * HH,
                                      hbuf, flags + NGRP * 32);
}

// Round 5
// 2742.862 us; speedup vs baseline: 10.4546x; 2.2282x over previous
//
#include <hip/hip_runtime.h>
#include <math.h>

#define BB 64
#define SS 512
#define EE 256
#define HH 512

#define NGRP 32    // independent batch-chunk groups (2 batches each)
#define GSZ  8     // row-slice blocks per group
#define NBLK (NGRP * GSZ)   // 256 blocks -> all 256 CUs

// ---------------------------------------------------------------------------
// Projection GEMM: out[m][n] = sum_k A[m][k] * Wih[n][k] + b1[n] + b2[n]
// ---------------------------------------------------------------------------
template <int K>
__global__ __launch_bounds__(256) void k_proj(const float* __restrict__ Ain,
                                              const int* __restrict__ src,
                                              const float* __restrict__ emb,
                                              const float* __restrict__ Wih,
                                              const float* __restrict__ b1,
                                              const float* __restrict__ b2,
                                              float* __restrict__ out) {
    __shared__ __align__(16) float As[16][68];
    __shared__ __align__(16) float Bs[16][68];
    int tid = threadIdx.x;
    int m0 = blockIdx.x * 64;
    int n0 = blockIdx.y * 64;
    int tx = tid & 15, ty = tid >> 4;
    int lr = tid >> 2;
    int lc = (tid & 3) * 4;

    const float* arow;
    if (src) arow = emb + (size_t)src[m0 + lr] * EE;
    else     arow = Ain + (size_t)(m0 + lr) * K;
    const float* brow = Wih + (size_t)(n0 + lr) * K;

    float acc[4][4] = {};

    for (int k0 = 0; k0 < K; k0 += 16) {
        float4 av = *(const float4*)(arow + k0 + lc);
        float4 bv = *(const float4*)(brow + k0 + lc);
        __syncthreads();
        As[lc + 0][lr] = av.x; As[lc + 1][lr] = av.y;
        As[lc + 2][lr] = av.z; As[lc + 3][lr] = av.w;
        Bs[lc + 0][lr] = bv.x; Bs[lc + 1][lr] = bv.y;
        Bs[lc + 2][lr] = bv.z; Bs[lc + 3][lr] = bv.w;
        __syncthreads();
#pragma unroll
        for (int k = 0; k < 16; ++k) {
            float4 a = *(const float4*)&As[k][ty * 4];
            float4 b = *(const float4*)&Bs[k][tx * 4];
            acc[0][0] += a.x * b.x; acc[0][1] += a.x * b.y;
            acc[0][2] += a.x * b.z; acc[0][3] += a.x * b.w;
            acc[1][0] += a.y * b.x; acc[1][1] += a.y * b.y;
            acc[1][2] += a.y * b.z; acc[1][3] += a.y * b.w;
            acc[2][0] += a.z * b.x; acc[2][1] += a.z * b.y;
            acc[2][2] += a.z * b.z; acc[2][3] += a.z * b.w;
            acc[3][0] += a.w * b.x; acc[3][1] += a.w * b.y;
            acc[3][2] += a.w * b.z; acc[3][3] += a.w * b.w;
        }
    }

    int n = n0 + tx * 4;
    float bx_ = b1[n + 0] + b2[n + 0];
    float by_ = b1[n + 1] + b2[n + 1];
    float bz_ = b1[n + 2] + b2[n + 2];
    float bw_ = b1[n + 3] + b2[n + 3];
#pragma unroll
    for (int i = 0; i < 4; ++i) {
        int m = m0 + ty * 4 + i;
        float4 o;
        o.x = acc[i][0] + bx_; o.y = acc[i][1] + by_;
        o.z = acc[i][2] + bz_; o.w = acc[i][3] + bw_;
        *(float4*)(out + (size_t)m * HH + n) = o;
    }
}

// ---------------------------------------------------------------------------
// Persistent recurrence, tag-in-data exchange (no flags, no drains).
// Grid = 256 blocks = 32 groups (2 batches) x 8 row-slices (64 rows).
// 256 threads = 64 lanes (row r) x 4 waves (k-quarter w).
// W slice (64x512) in 128 regs/thread (VGPR+AGPR unified file).
// h published as {f32 val, u32 tag=t+1} 8B relaxed agent atomics (IC-coherent,
// per-8B atomic => no ordering/drain needed). Consumers retry-load until all
// their tags == t. 2-slot buffer safe: slot overwritten 2 steps later, and
// producing step t implies having consumed step t-1.
// Poison 0xAA != any tag in [1,512]; per-layer buffers avoid tag collisions.
// ---------------------------------------------------------------------------
__global__ __launch_bounds__(256, 1) void k_rec_p(const float* __restrict__ pre,
                                                  const float* __restrict__ W,
                                                  float* __restrict__ y,
                                                  float* __restrict__ hlast,
                                                  unsigned long long* __restrict__ hp) {
    __shared__ __align__(16) float h_lds[2 * HH];      // 2 batches x 512
    __shared__ __align__(16) float red[4][2][64];      // [kq][batch][row]
    const int tid = threadIdx.x;
    const int r = tid & 63;
    const int w = tid >> 6;          // k-quarter (and batch index if w<2)
    const int bid = blockIdx.x;
    const int g = bid & 7;           // row slice 0..7 (consecutive bids -> XCD spread)
    const int c = bid >> 3;          // batch chunk 0..31
    const int grow = g * 64 + r;     // global output row
    const int b = c * 2 + (w & 1);   // batch for finalize (valid when w<2)

    // W slice -> registers (one-time)
    float4 w4[32];
    const float* wrow = W + (size_t)grow * HH + w * 128;
#pragma unroll
    for (int i = 0; i < 32; ++i) w4[i] = *(const float4*)(wrow + i * 4);

    // ---- t = 0: h = tanh(pre); publish tag 1 into slot 1 ----
    float hval = 0.f;
    if (w < 2) {
        float pv = pre[(size_t)b * SS * HH + grow];
        hval = tanhf(pv);
        y[(size_t)b * SS * HH + grow] = hval;
        unsigned long long pk = ((unsigned long long)1u << 32) |
                                (unsigned long long)__float_as_uint(hval);
        __hip_atomic_store(&hp[(size_t)1 * BB * HH + (size_t)b * HH + grow], pk,
                           __ATOMIC_RELAXED, __HIP_MEMORY_SCOPE_AGENT);
    }

    const int j = tid * 4;           // this thread's 4 pairs within the chunk

    for (int t = 1; t < SS; ++t) {
        float pv = 0.f;
        if (w < 2) pv = pre[((size_t)b * SS + t) * HH + grow];  // hides under retry

        // consume h_{t-1}: 1024 pairs for our 2 batches, tags must equal t
        const unsigned long long* srcp =
            hp + (size_t)(t & 1) * BB * HH + (size_t)(c * 2) * HH;
        unsigned long long p0, p1, p2, p3;
        const unsigned tt = (unsigned)t;
        for (;;) {
            p0 = __hip_atomic_load(&srcp[j + 0], __ATOMIC_RELAXED, __HIP_MEMORY_SCOPE_AGENT);
            p1 = __hip_atomic_load(&srcp[j + 1], __ATOMIC_RELAXED, __HIP_MEMORY_SCOPE_AGENT);
            p2 = __hip_atomic_load(&srcp[j + 2], __ATOMIC_RELAXED, __HIP_MEMORY_SCOPE_AGENT);
            p3 = __hip_atomic_load(&srcp[j + 3], __ATOMIC_RELAXED, __HIP_MEMORY_SCOPE_AGENT);
            unsigned d = (((unsigned)(p0 >> 32)) ^ tt) | (((unsigned)(p1 >> 32)) ^ tt) |
                         (((unsigned)(p2 >> 32)) ^ tt) | (((unsigned)(p3 >> 32)) ^ tt);
            if (d == 0) break;
        }
        float4 hv;
        hv.x = __uint_as_float((unsigned)p0);
        hv.y = __uint_as_float((unsigned)p1);
        hv.z = __uint_as_float((unsigned)p2);
        hv.w = __uint_as_float((unsigned)p3);
        *(float4*)&h_lds[j] = hv;
        __syncthreads();

        float acc0 = 0.f, acc1 = 0.f;
        const float4* h0p = (const float4*)h_lds + w * 32;          // batch c*2
        const float4* h1p = (const float4*)(h_lds + HH) + w * 32;   // batch c*2+1
#pragma unroll
        for (int i = 0; i < 32; ++i) {
            const float4 a = w4[i];
            const float4 x0 = h0p[i];
            const float4 x1 = h1p[i];
            acc0 += a.x * x0.x; acc0 += a.y * x0.y; acc0 += a.z * x0.z; acc0 += a.w * x0.w;
            acc1 += a.x * x1.x; acc1 += a.y * x1.y; acc1 += a.z * x1.z; acc1 += a.w * x1.w;
        }
        red[w][0][r] = acc0; red[w][1][r] = acc1;
        __syncthreads();

        if (w < 2) {
            float s = red[0][w][r] + red[1][w][r] + red[2][w][r] + red[3][w][r];
            hval = tanhf(pv + s);
            y[((size_t)b * SS + t) * HH + grow] = hval;
            if (t < SS - 1) {
                unsigned long long pk = ((unsigned long long)(unsigned)(t + 1) << 32) |
                                        (unsigned long long)__float_as_uint(hval);
                __hip_atomic_store(&hp[(size_t)((t + 1) & 1) * BB * HH + (size_t)b * HH + grow],
                                   pk, __ATOMIC_RELAXED, __HIP_MEMORY_SCOPE_AGENT);
            }
        }
    }
    if (w < 2) hlast[(size_t)b * HH + grow] = hval;
}

// ---------------------------------------------------------------------------
extern "C" void kernel_launch(void* const* d_in, const int* in_sizes, int n_in,
                              void* d_out, int out_size, void* d_ws, size_t ws_size,
                              hipStream_t stream) {
    const int*   src   = (const int*)d_in[0];
    const float* emb   = (const float*)d_in[1];
    const float* W_ih0 = (const float*)d_in[2];
    const float* W_hh0 = (const float*)d_in[3];
    const float* b_ih0 = (const float*)d_in[4];
    const float* b_hh0 = (const float*)d_in[5];
    const float* W_ih1 = (const float*)d_in[6];
    const float* W_hh1 = (const float*)d_in[7];
    const float* b_ih1 = (const float*)d_in[8];
    const float* b_hh1 = (const float*)d_in[9];

    float* out   = (float*)d_out;
    float* y_out = out;                               // [B][S][H]
    float* hlast = out + (size_t)BB * SS * HH;        // [2][B][H]

    float* ws  = (float*)d_ws;
    float* pre = ws;                                  // [B][S][H]
    unsigned long long* hp0 = (unsigned long long*)(ws + (size_t)BB * SS * HH);
    unsigned long long* hp1 = hp0 + (size_t)2 * BB * HH;   // separate layer buffers
    // No memset needed: 0xAA poison never matches tags 1..511, and per-layer
    // buffers prevent layer-0 leftover tags from validating layer-1 reads.

    // Layer 0
    k_proj<EE><<<dim3(512, 8), 256, 0, stream>>>(nullptr, src, emb, W_ih0,
                                                 b_ih0, b_hh0, pre);
    k_rec_p<<<NBLK, 256, 0, stream>>>(pre, W_hh0, y_out, hlast, hp0);

    // Layer 1
    k_proj<HH><<<dim3(512, 8), 256, 0, stream>>>(y_out, nullptr, nullptr, W_ih1,
                                                 b_ih1, b_hh1, pre);
    k_rec_p<<<NBLK, 256, 0, stream>>>(pre, W_hh1, y_out, hlast + (size_t)BB * HH, hp1);
}